// Round 1
// baseline (1329.553 us; speedup 1.0000x reference)
//
#include <hip/hip_runtime.h>
#include <stdint.h>

// ---------------------------------------------------------------------------
// IsoMaxPlus distances: out[n,c] = -|scale| * sqrt(max(2 - 2*<f_n, p_c>, 1e-12))
// with f, p L2-normalized rows. Implemented as:
//   1) row-normalize features -> bf16 in ws           [N=16384, D=2048]
//   2) row-normalize prototypes -> bf16 in ws         [C=8192,  D=2048]
//   3) bf16 MFMA GEMM (B^T layout) + fused epilogue   [N, C] fp32
// ---------------------------------------------------------------------------

#define D_DIM 2048
#define BM 128
#define BN 128
#define BK 32

typedef short bf16x8 __attribute__((ext_vector_type(8)));
typedef float f32x4 __attribute__((ext_vector_type(4)));

__device__ __forceinline__ unsigned short f32_to_bf16(float f) {
  unsigned u = __float_as_uint(f);
  unsigned r = 0x7FFFu + ((u >> 16) & 1u);   // round-to-nearest-even
  return (unsigned short)((u + r) >> 16);
}

// one block per row, 256 threads, D = 2048 (8 floats/thread via 2x float4)
__global__ __launch_bounds__(256) void norm_rows_kernel(
    const float* __restrict__ in, unsigned short* __restrict__ out) {
  const int row = blockIdx.x;
  const int t = threadIdx.x;
  const float4* rp = (const float4*)(in + (size_t)row * D_DIM);
  float4 a = rp[t];
  float4 b = rp[t + 256];
  float ss = a.x * a.x + a.y * a.y + a.z * a.z + a.w * a.w +
             b.x * b.x + b.y * b.y + b.z * b.z + b.w * b.w;
#pragma unroll
  for (int off = 32; off > 0; off >>= 1) ss += __shfl_down(ss, off, 64);
  __shared__ float sred[4];
  if ((t & 63) == 0) sred[t >> 6] = ss;
  __syncthreads();
  float tot = sred[0] + sred[1] + sred[2] + sred[3];
  float inv = 1.0f / fmaxf(sqrtf(tot), 1e-12f);
  ushort4 oa, ob;
  oa.x = f32_to_bf16(a.x * inv);
  oa.y = f32_to_bf16(a.y * inv);
  oa.z = f32_to_bf16(a.z * inv);
  oa.w = f32_to_bf16(a.w * inv);
  ob.x = f32_to_bf16(b.x * inv);
  ob.y = f32_to_bf16(b.y * inv);
  ob.z = f32_to_bf16(b.z * inv);
  ob.w = f32_to_bf16(b.w * inv);
  ushort4* op = (ushort4*)(out + (size_t)row * D_DIM);
  op[t] = oa;
  op[t + 256] = ob;
}

// async 16B global -> LDS (wave-uniform LDS base; lane data lands at base+lane*16)
__device__ __forceinline__ void async_load16(const void* gptr, uint32_t lds_off,
                                             void* lds_base) {
  typedef __attribute__((address_space(3))) uint32_t lds_u32_t;
  typedef const __attribute__((address_space(1))) uint32_t glb_u32_t;
  glb_u32_t* g = reinterpret_cast<glb_u32_t*>(reinterpret_cast<uintptr_t>(gptr));
  lds_u32_t* l = reinterpret_cast<lds_u32_t*>(
      (uint32_t)(reinterpret_cast<uintptr_t>(lds_base) + lds_off));
  __builtin_amdgcn_global_load_lds(g, l, 16, 0, 0);
}

// C = A * B^T, A [N][K] bf16, B [C][K] bf16, fused distance epilogue.
// 128x128 block tile, 4 waves each computing a 64x64 quadrant as 4x4 MFMA
// 16x16x32 tiles. LDS tiles [128][32] bf16, unpadded (global_load_lds needs
// contiguous per-wave layout).
__global__ __launch_bounds__(256) void gemm_bt_dist(
    const unsigned short* __restrict__ A, const unsigned short* __restrict__ B,
    float* __restrict__ Out, const float* __restrict__ scale_ptr, int N, int C,
    int K) {
  __shared__ __align__(16) unsigned short sA[BM * BK];
  __shared__ __align__(16) unsigned short sB[BN * BK];

  const int tid = threadIdx.x;
  const int wave = tid >> 6;
  const int lane = tid & 63;

  const int m0 = blockIdx.y * BM;
  const int n0 = blockIdx.x * BN;

  // staging: tile = 128 rows x 64 B; thread q covers 16B chunk q (issue 0:
  // rows 0-63, issue 1: rows 64-127)
  const int srow = tid >> 2;          // 0..63
  const int scol = (tid & 3) * 8;     // element offset within row
  const unsigned short* gA0 = A + (size_t)(m0 + srow) * K + scol;
  const unsigned short* gA1 = A + (size_t)(m0 + 64 + srow) * K + scol;
  const unsigned short* gB0 = B + (size_t)(n0 + srow) * K + scol;
  const unsigned short* gB1 = B + (size_t)(n0 + 64 + srow) * K + scol;
  const uint32_t ldsw = (uint32_t)(wave * 1024);  // wave-uniform base, bytes

  const int mq = (wave >> 1) * 64;  // wave's m-quadrant within tile
  const int nq = (wave & 1) * 64;   // wave's n-quadrant
  const int frow = lane & 15;       // fragment row (A) / col (B)
  const int fk = (lane >> 4) * 8;   // fragment k element offset

  f32x4 acc[4][4] = {};

  for (int k0 = 0; k0 < K; k0 += BK) {
    __syncthreads();  // all waves done reading previous tile
    async_load16(gA0 + k0, ldsw, sA);
    async_load16(gA1 + k0, 4096u + ldsw, sA);
    async_load16(gB0 + k0, ldsw, sB);
    async_load16(gB1 + k0, 4096u + ldsw, sB);
    __syncthreads();  // compiler emits vmcnt(0) drain before barrier

    bf16x8 af[4], bfr[4];
#pragma unroll
    for (int i = 0; i < 4; ++i) {
      af[i] = *(const bf16x8*)(sA + (mq + i * 16 + frow) * BK + fk);
      bfr[i] = *(const bf16x8*)(sB + (nq + i * 16 + frow) * BK + fk);
    }
#pragma unroll
    for (int i = 0; i < 4; ++i)
#pragma unroll
      for (int j = 0; j < 4; ++j)
        acc[i][j] = __builtin_amdgcn_mfma_f32_16x16x32_bf16(af[i], bfr[j],
                                                            acc[i][j], 0, 0, 0);
  }

  // epilogue: C/D layout col=lane&15, row=(lane>>4)*4+reg  [m89/m91]
  const float s = fabsf(scale_ptr[0]);
  const int ocol = n0 + nq + (lane & 15);
  const int orow = m0 + mq + (lane >> 4) * 4;
#pragma unroll
  for (int i = 0; i < 4; ++i) {
#pragma unroll
    for (int j = 0; j < 4; ++j) {
#pragma unroll
      for (int r = 0; r < 4; ++r) {
        float sim = acc[i][j][r];
        float sq = fmaxf(2.0f - 2.0f * sim, 1e-12f);
        Out[(size_t)(orow + i * 16 + r) * C + (ocol + j * 16)] =
            -s * sqrtf(sq);
      }
    }
  }
}

extern "C" void kernel_launch(void* const* d_in, const int* in_sizes, int n_in,
                              void* d_out, int out_size, void* d_ws,
                              size_t ws_size, hipStream_t stream) {
  const float* feats = (const float*)d_in[0];   // [N, 2048] fp32
  const float* protos = (const float*)d_in[1];  // [C, 2048] fp32
  const float* dscale = (const float*)d_in[2];  // [1] fp32
  float* out = (float*)d_out;                   // [N, C] fp32

  const int N = in_sizes[0] / D_DIM;  // 16384
  const int C = in_sizes[1] / D_DIM;  // 8192
  const int K = D_DIM;

  unsigned short* fb = (unsigned short*)d_ws;           // [N][K] bf16
  unsigned short* pb = fb + (size_t)N * D_DIM;          // [C][K] bf16

  norm_rows_kernel<<<N, 256, 0, stream>>>(feats, fb);
  norm_rows_kernel<<<C, 256, 0, stream>>>(protos, pb);

  dim3 grid(C / BN, N / BM);
  gemm_bt_dist<<<grid, 256, 0, stream>>>(fb, pb, out, dscale, N, C, K);
}